// Round 13
// baseline (199.138 us; speedup 1.0000x reference)
//
#include <hip/hip_runtime.h>
#include <hip/hip_bf16.h>

typedef __bf16 bf16_t;
typedef __bf16 bf16x8 __attribute__((ext_vector_type(8)));
typedef float  f32x4  __attribute__((ext_vector_type(4)));
typedef unsigned short ushort_t;
typedef unsigned int uint_t;

#define MFMA16(a, b, c) __builtin_amdgcn_mfma_f32_16x16x32_bf16((a), (b), (c), 0, 0, 0)
// async global->LDS, 16B/lane, dst = wave-uniform base + lane*16
#define GLDS16(g, l) __builtin_amdgcn_global_load_lds( \
    (const __attribute__((address_space(1))) unsigned int*)(g), \
    (__attribute__((address_space(3))) unsigned int*)(l), 16, 0, 0)

// s_waitcnt imm (gfx9): vmcnt[3:0] | exp[6:4] | lgkm[11:8] | vmcnt_hi[15:14]
#define WAITCNT_VM(n)  (0x0F70 | (n))   // vmcnt(n), exp/lgkm no-wait (n<16)
#define WAITCNT_LGKM0  0xC07F           // lgkmcnt(0), vm/exp no-wait

#define MEMFENCE asm volatile("" ::: "memory")

// granule swizzle for 8-elem (16B) granules within a [..][32] LDS row:
// global granule b of row r stored at position b ^ SWZ(r).
#define SWZ(r) ((((r) >> 1) ^ ((r) >> 3)) & 3)

// Problem: B=2, S=2048, D=1024, H=16, HD=64, M = B*S = 4096
// Softmax scale folded into Q at QKV epilogue: 0.125 * log2(e)
#define QSCALE 0.18033688f

// ---------------------------------------------------------------------------
// Fused conversion: local dtype-sniff per block (no extra dispatch), then
// X (2048 blocks) | weights (2048 blocks) | biases+flag (2 blocks).
// ---------------------------------------------------------------------------
__global__ __launch_bounds__(256) void cvt_all(
    const void* __restrict__ X,  const void* __restrict__ W0, const void* __restrict__ W1,
    const void* __restrict__ W2, const void* __restrict__ W3,
    const void* __restrict__ c0, const void* __restrict__ c1,
    const void* __restrict__ c2, const void* __restrict__ c3,
    bf16_t* __restrict__ Xb, bf16_t* __restrict__ Wb, float* __restrict__ biasF,
    int* __restrict__ flag)
{
    const int tid  = threadIdx.x;
    const int lane = tid & 63;
    const ushort_t u = ((const ushort_t*)X)[2 * lane];
    const int e = (u >> 7) & 0xFF;
    const int f = (__ballot(e >= 0xA0) != 0ull) ? 1 : 0;

    const int bid = blockIdx.x;
    if (bid >= 4096) {   // bias blocks
        if (bid == 4096 && tid == 0) *flag = f;
        const int idx = ((bid - 4096) * 256 + tid) * 8;   // 0..4095, chunks of 8
        const int w = idx >> 10, off = idx & 1023;
        const void* src = (w == 0) ? c0 : (w == 1) ? c1 : (w == 2) ? c2 : c3;
        #pragma unroll
        for (int r = 0; r < 8; ++r)
            biasF[idx + r] = f ? ((const float*)src)[off + r]
                               : (float)((const bf16_t*)src)[off + r];
        return;
    }

    const long long i = (long long)bid * 2048 + tid * 8;
    const void* src;
    bf16_t* dst;
    long long off;
    if (i < 4194304) { src = X; dst = Xb; off = i; }
    else {
        const int w = (int)((i - 4194304) >> 20);
        off = (i - 4194304) & 1048575;
        src = (w == 0) ? W0 : (w == 1) ? W1 : (w == 2) ? W2 : W3;
        dst = Wb + (size_t)w * 1048576;
    }
    if (f) {
        const float* s = (const float*)src + off;
        const float4 a = *(const float4*)(s);
        const float4 b = *(const float4*)(s + 4);
        bf16x8 o;
        o[0] = (bf16_t)a.x; o[1] = (bf16_t)a.y; o[2] = (bf16_t)a.z; o[3] = (bf16_t)a.w;
        o[4] = (bf16_t)b.x; o[5] = (bf16_t)b.y; o[6] = (bf16_t)b.z; o[7] = (bf16_t)b.w;
        *(bf16x8*)(dst + off) = o;
    } else {
        *(bf16x8*)(dst + off) = *(const bf16x8*)((const bf16_t*)src + off);
    }
}

// ---------------------------------------------------------------------------
// QKV GEMM (r9 structure, frozen): 256x192 tile -> grid (16,16) = 256 blocks
// = 1/CU, all CUs busy. One barrier per 32-col half; stacked Wb[3072][1024]
// and biasF[3072]; wave-dependent counted vmcnt. LDS 112KB.
// Measured: 44.3-46.2 us, MfmaUtil ~21, 0 bank conflicts. Plateau.
// ---------------------------------------------------------------------------
__global__ __launch_bounds__(512, 2) void gemm_qkv(
    const bf16_t* __restrict__ A,
    const bf16_t* __restrict__ Wst,      // stacked [3072][1024]
    const float* __restrict__ biasAll,   // stacked [3072]
    bf16_t* __restrict__ C, bf16_t* __restrict__ Vt)
{
    __shared__ bf16_t Ash[4][256 * 32];
    __shared__ bf16_t Bsh[4][192 * 32];

    const int tid  = threadIdx.x;
    const int wid  = tid >> 6;       // 0..7
    const int lane = tid & 63;
    const int g    = lane >> 4;
    const int c    = lane & 15;

    const int m0 = blockIdx.x * 256;
    const int n0 = blockIdx.y * 192;

    // staging: one GLDS call = 16 rows x 32 cols (1KB)
    const int srow = lane >> 2;                        // 0..15
    const int sblk = (lane & 3) ^ ((lane >> 3) & 3);   // pre-swizzled source blk
    const bf16_t* Ag  = A   + (size_t)(m0 + wid * 32 + srow) * 1024 + sblk * 8;
    const bf16_t* Wg0 = Wst + (size_t)(n0 + wid * 16 + srow) * 1024 + sblk * 8;
    const bf16_t* Wg1 = Wst + (size_t)(n0 + 128 + wid * 16 + srow) * 1024 + sblk * 8;

    const int waveM = (wid >> 2) * 128;   // 2 waves in M
    const int waveN = (wid & 3) * 48;     // 4 waves in N (48 cols each)
    const int fblk  = (g ^ ((c >> 1) & 3)) * 8;

    f32x4 acc[8][3] = {};

    auto stage = [&](int H) {
        const int buf = H & 3;
        GLDS16(Ag + H * 32,                      &Ash[buf][(wid * 32) * 32]);
        GLDS16(Ag + (size_t)16 * 1024 + H * 32,  &Ash[buf][(wid * 32 + 16) * 32]);
        GLDS16(Wg0 + H * 32,                     &Bsh[buf][(wid * 16) * 32]);
        if (wid < 4)
            GLDS16(Wg1 + H * 32,                 &Bsh[buf][(128 + wid * 16) * 32]);
    };

    // prologue: halves 0,1,2 in flight; retire half 0 only (2 halves stay out)
    stage(0); stage(1); stage(2);
    if (wid < 4) __builtin_amdgcn_s_waitcnt(WAITCNT_VM(8));
    else         __builtin_amdgcn_s_waitcnt(WAITCNT_VM(6));
    __builtin_amdgcn_s_barrier();
    MEMFENCE;

    #pragma unroll 4
    for (int H = 0; H < 32; ++H) {
        const int buf = H & 3;
        const bf16_t* As = Ash[buf];
        const bf16_t* Bs = Bsh[buf];

        bf16x8 bfr[3], af[8];
        #pragma unroll
        for (int j = 0; j < 3; ++j)
            bfr[j] = *(const bf16x8*)(&Bs[(waveN + j * 16 + c) * 32 + fblk]);
        #pragma unroll
        for (int i = 0; i < 8; ++i)
            af[i] = *(const bf16x8*)(&As[(waveM + i * 16 + c) * 32 + fblk]);

        if (H < 29) stage(H + 3);

        __builtin_amdgcn_s_setprio(1);
        #pragma unroll
        for (int i = 0; i < 8; ++i)
            #pragma unroll
            for (int j = 0; j < 3; ++j)
                acc[i][j] = MFMA16(af[i], bfr[j], acc[i][j]);
        __builtin_amdgcn_s_setprio(0);

        MEMFENCE;
        __builtin_amdgcn_s_waitcnt(WAITCNT_LGKM0);   // my LDS reads retired
        if (H < 29) {        // half H+1 resident (2 halves' loads may remain)
            if (wid < 4) __builtin_amdgcn_s_waitcnt(WAITCNT_VM(8));
            else         __builtin_amdgcn_s_waitcnt(WAITCNT_VM(6));
        } else if (H == 29) {
            if (wid < 4) __builtin_amdgcn_s_waitcnt(WAITCNT_VM(4));
            else         __builtin_amdgcn_s_waitcnt(WAITCNT_VM(3));
        } else if (H == 30) {
            __builtin_amdgcn_s_waitcnt(WAITCNT_VM(0));
        }
        __builtin_amdgcn_s_barrier();
        MEMFENCE;
    }

    #pragma unroll
    for (int j = 0; j < 3; ++j) {
        const int cg0 = n0 + waveN + j * 16;      // 16-aligned -> uniform branch
        const int col = cg0 + c;
        const float bv = biasAll[col];
        if (cg0 >= 2048) {
            // V^T: Vt[((b*16+h)*64 + d)*2048 + s]; 4 consecutive s per store
            const int hcol = col - 2048;
            const int h = hcol >> 6, d = hcol & 63;
            #pragma unroll
            for (int i = 0; i < 8; ++i) {
                const int row = m0 + waveM + i * 16 + g * 4;
                const int bb = row >> 11, s = row & 2047;
                bf16_t pk[4];
                #pragma unroll
                for (int r = 0; r < 4; ++r) pk[r] = (bf16_t)(acc[i][j][r] + bv);
                *(uint2*)(&Vt[(((size_t)bb * 16 + h) * 64 + d) * 2048 + s]) = *(uint2*)pk;
            }
        } else {
            const float os = (cg0 < 1024) ? QSCALE : 1.0f;   // pre-scale Q
            #pragma unroll
            for (int i = 0; i < 8; ++i) {
                const int row = m0 + waveM + i * 16 + g * 4;
                #pragma unroll
                for (int r = 0; r < 4; ++r)
                    C[(size_t)(row + r) * 3072 + col] = (bf16_t)((acc[i][j][r] + bv) * os);
            }
        }
    }
}

// ---------------------------------------------------------------------------
// Out-proj GEMM (r12, frozen): 128x128 tile, BK=64 -> 16 K-steps, grid
// (32,8) = 256 blocks = 1/CU, 3 LDS buffers (96KB), 2-deep counted prefetch.
// Dropped out of top-5 in r12 (<=44us, was 52 as gemm_nt).
// ---------------------------------------------------------------------------
__global__ __launch_bounds__(512, 1) void gemm_op(
    const bf16_t* __restrict__ A,
    const bf16_t* __restrict__ W,
    const float* __restrict__ bs,
    void* __restrict__ C,
    const int* __restrict__ flag)
{
    __shared__ bf16_t As[3][2][128 * 32];   // [buf][khalf][row*32]
    __shared__ bf16_t Bs[3][2][128 * 32];

    const int f32out = *flag;

    const int tid  = threadIdx.x;
    const int wid  = tid >> 6;       // 0..7
    const int lane = tid & 63;
    const int g    = lane >> 4;
    const int c    = lane & 15;

    const int m0 = blockIdx.x * 128;
    const int n0 = blockIdx.y * 128;

    // staging: one GLDS call = 16 rows x 32 cols (1KB); wave w -> rows w*16..+15
    const int srow = lane >> 2;                        // 0..15
    const int sblk = (lane & 3) ^ ((lane >> 3) & 3);   // pre-swizzled source blk
    const bf16_t* Ag = A + (size_t)(m0 + wid * 16 + srow) * 1024 + sblk * 8;
    const bf16_t* Wg = W + (size_t)(n0 + wid * 16 + srow) * 1024 + sblk * 8;

    const int waveM = (wid >> 2) * 64;    // 2 waves in M (64 rows each)
    const int waveN = (wid & 3) * 32;     // 4 waves in N (32 cols each)
    const int fblk  = (g ^ ((c >> 1) & 3)) * 8;

    f32x4 acc[4][2] = {};

    auto stage = [&](int t) {              // t = K-step (64 cols); 4 calls/wave
        const int buf = t % 3;
        const size_t k0 = (size_t)t * 64;
        GLDS16(Ag + k0,      &As[buf][0][(wid * 16) * 32]);
        GLDS16(Ag + k0 + 32, &As[buf][1][(wid * 16) * 32]);
        GLDS16(Wg + k0,      &Bs[buf][0][(wid * 16) * 32]);
        GLDS16(Wg + k0 + 32, &Bs[buf][1][(wid * 16) * 32]);
    };

    // prologue: steps 0,1 in flight; retire step 0 only (1 buffer stays out)
    stage(0); stage(1);
    __builtin_amdgcn_s_waitcnt(WAITCNT_VM(4));
    __builtin_amdgcn_s_barrier();
    MEMFENCE;

    #pragma unroll 3
    for (int s = 0; s < 16; ++s) {
        const int buf = s % 3;

        if (s < 14) stage(s + 2);

        __builtin_amdgcn_s_setprio(1);
        #pragma unroll
        for (int kh = 0; kh < 2; ++kh) {
            bf16x8 af[4], bfr[2];
            #pragma unroll
            for (int i = 0; i < 4; ++i)
                af[i] = *(const bf16x8*)(&As[buf][kh][(waveM + i * 16 + c) * 32 + fblk]);
            #pragma unroll
            for (int j = 0; j < 2; ++j)
                bfr[j] = *(const bf16x8*)(&Bs[buf][kh][(waveN + j * 16 + c) * 32 + fblk]);
            #pragma unroll
            for (int i = 0; i < 4; ++i)
                #pragma unroll
                for (int j = 0; j < 2; ++j)
                    acc[i][j] = MFMA16(af[i], bfr[j], acc[i][j]);
        }
        __builtin_amdgcn_s_setprio(0);

        MEMFENCE;
        __builtin_amdgcn_s_waitcnt(WAITCNT_LGKM0);              // my LDS reads retired
        if (s < 14)       __builtin_amdgcn_s_waitcnt(WAITCNT_VM(4));  // step s+1 resident
        else if (s == 14) __builtin_amdgcn_s_waitcnt(WAITCNT_VM(0));
        __builtin_amdgcn_s_barrier();
        MEMFENCE;
    }

    #pragma unroll
    for (int j = 0; j < 2; ++j) {
        const int col = n0 + waveN + j * 16 + c;
        const float bv = bs[col];
        #pragma unroll
        for (int i = 0; i < 4; ++i) {
            const int row = m0 + waveM + i * 16 + g * 4;
            #pragma unroll
            for (int r = 0; r < 4; ++r) {
                const float val = acc[i][j][r] + bv;
                const size_t idx = (size_t)(row + r) * 1024 + col;
                if (f32out) ((float*)C)[idx] = val;
                else        ((bf16_t*)C)[idx] = (bf16_t)val;
            }
        }
    }
}

// ---------------------------------------------------------------------------
// Causal flash attention, r13: swapped-operand form + P-VIA-SHUFFLE + K/V
// DOUBLE-BUFFER + ONE sync/tile.
// - P redistribution for PV is a pure lane-bit-4/5 permutation: target (g,c)
//   needs p[n=2kb+(g>>1)][r] from source lanes (2(g&1)+b, c) -> 8 __shfl +
//   4 selects per kb, fully in-register (replaces 4 ds_write + 4 ds_read +
//   wave_barrier; derived from and equal to the verified r11 granule map).
// - Psh freed (9KB) -> K/V dbuf fits in 32KB -> nt+1 syncs instead of 2*nt,
//   4-5 blocks/CU retained (r4's dbuf failure was 46KB/3-blocks + conflicts).
// ---------------------------------------------------------------------------
__global__ __launch_bounds__(256, 4) void attn_kernel(
    const bf16_t* __restrict__ QKV, const bf16_t* __restrict__ Vt,
    bf16_t* __restrict__ O)
{
    __shared__ bf16_t Ksh[2][2][64][32];   // [buf][kb][row][32]
    __shared__ bf16_t Vsh[2][2][64][32];

    const int tid  = threadIdx.x;
    const int wid  = tid >> 6;
    const int lane = tid & 63;
    const int g    = lane >> 4;
    const int c    = lane & 15;

    const int bh = blockIdx.y;
    const int b  = bh >> 4, h = bh & 15;
    const int qt = (bh < 16) ? blockIdx.x : (31 - blockIdx.x);
    const int q0 = qt * 64;
    const int nt = qt + 1;   // # of 64-key tiles

    bf16x8 aq[2];
    {
        const bf16_t* qp = QKV + (size_t)(b * 2048 + q0 + wid * 16 + c) * 3072 + h * 64;
        aq[0] = *(const bf16x8*)(qp + g * 8);
        aq[1] = *(const bf16x8*)(qp + 32 + g * 8);
    }

    float li = 0.0f;     // partial softmax denom for q = c (lane-local row)
    f32x4 o2[4] = {};    // o2[dt][r] = O[q=c][d = dt*16 + g*4 + r]

    // staging: thread -> row sr (0..63), granules j4 (kb=0) and j4+4 (kb=1)
    const int sr = tid >> 2;
    const int j4 = tid & 3;
    const bf16_t* Kg = QKV + (size_t)(b * 2048 + sr) * 3072 + 1024 + h * 64 + j4 * 8;
    const bf16_t* Vg = Vt + ((size_t)bh * 64 + sr) * 2048 + j4 * 8;

    const int sp = (j4 ^ SWZ(sr)) * 8;   // swizzled granule pos (same both kb)

    uint4 kr0 = *(const uint4*)(Kg);
    uint4 kr1 = *(const uint4*)(Kg + 32);
    uint4 vr0 = *(const uint4*)(Vg);
    uint4 vr1 = *(const uint4*)(Vg + 32);

    // prologue: tile 0 -> buf 0
    *(uint4*)(&Ksh[0][0][sr][sp]) = kr0;
    *(uint4*)(&Ksh[0][1][sr][sp]) = kr1;
    *(uint4*)(&Vsh[0][0][sr][sp]) = vr0;
    *(uint4*)(&Vsh[0][1][sr][sp]) = vr1;
    __syncthreads();

    const int qg = q0 + wid * 16 + c;    // this lane's global q row

    for (int jt = 0; jt < nt; ++jt) {
        const int cur = jt & 1;

        if (jt + 1 < nt) {   // register prefetch of next tile (overlaps compute)
            const size_t ko = (size_t)(jt + 1) * 64 * 3072;
            kr0 = *(const uint4*)(Kg + ko);
            kr1 = *(const uint4*)(Kg + ko + 32);
            vr0 = *(const uint4*)(Vg + (jt + 1) * 64);
            vr1 = *(const uint4*)(Vg + (jt + 1) * 64 + 32);
        }

        // QK^T swapped: s[n] = S^T fragment; lane holds S[q=c][key n*16+g*4+r]
        f32x4 s[4] = {};
        __builtin_amdgcn_s_setprio(1);
        #pragma unroll
        for (int n = 0; n < 4; ++n)
            #pragma unroll
            for (int kb = 0; kb < 2; ++kb) {
                const int row = n * 16 + c;
                const bf16x8 kf = *(const bf16x8*)(&Ksh[cur][kb][row][(g ^ SWZ(row)) * 8]);
                s[n] = MFMA16(kf, aq[kb], s[n]);
            }
        __builtin_amdgcn_s_setprio(0);

        if (jt == nt - 1) {   // diagonal tile: mask key > q
            const int j0 = jt * 64;
            #pragma unroll
            for (int n = 0; n < 4; ++n)
                #pragma unroll
                for (int r = 0; r < 4; ++r)
                    if (j0 + n * 16 + g * 4 + r > qg) s[n][r] = -1e30f;
        }

        // softmax: lane-local sum + pack p[n] into 2 u32 of 2xbf16 each
        uint_t pk[4][2];
        #pragma unroll
        for (int n = 0; n < 4; ++n) {
            const float p0 = __builtin_amdgcn_exp2f(s[n][0]);
            const float p1 = __builtin_amdgcn_exp2f(s[n][1]);
            const float p2 = __builtin_amdgcn_exp2f(s[n][2]);
            const float p3 = __builtin_amdgcn_exp2f(s[n][3]);
            li += (p0 + p1) + (p2 + p3);
            union { bf16_t h[2]; uint_t u; } t0, t1;
            t0.h[0] = (bf16_t)p0; t0.h[1] = (bf16_t)p1;
            t1.h[0] = (bf16_t)p2; t1.h[1] = (bf16_t)p3;
            pk[n][0] = t0.u; pk[n][1] = t1.u;
        }

        // P redistribution via shfl (lane-bit-4/5 permutation):
        // target (g,c) word pair b comes from src lane c + 32*(g&1) + 16*b;
        // n = 2kb + (g>>1) selected post-shfl.
        bf16x8 pb[2];
        const int src0 = c + ((lane & 16) << 1);     // c + 32*(g&1)
        const bool hi_g = (lane & 32) != 0;          // g>>1
        #pragma unroll
        for (int kb = 0; kb < 2; ++kb) {
            uint_t w[4];
            #pragma unroll
            for (int bsel = 0; bsel < 2; ++bsel) {
                const int src = src0 + bsel * 16;
                const uint_t lo0 = __shfl((int)pk[2 * kb][0], src, 64);
                const uint_t hi0 = __shfl((int)pk[2 * kb][1], src, 64);
                const uint_t lo1 = __shfl((int)pk[2 * kb + 1][0], src, 64);
                const uint_t hi1 = __shfl((int)pk[2 * kb + 1][1], src, 64);
                w[2 * bsel]     = hi_g ? lo1 : lo0;
                w[2 * bsel + 1] = hi_g ? hi1 : hi0;
            }
            union { uint_t u[4]; bf16x8 v; } cvt_;
            cvt_.u[0] = w[0]; cvt_.u[1] = w[1]; cvt_.u[2] = w[2]; cvt_.u[3] = w[3];
            pb[kb] = cvt_.v;
        }

        // PV swapped: o2[dt] = MFMA(vf, pb)
        __builtin_amdgcn_s_setprio(1);
        #pragma unroll
        for (int kb = 0; kb < 2; ++kb)
            #pragma unroll
            for (int dt = 0; dt < 4; ++dt) {
                const int row = dt * 16 + c;
                const bf16x8 vf = *(const bf16x8*)(&Vsh[cur][kb][row][(g ^ SWZ(row)) * 8]);
                o2[dt] = MFMA16(vf, pb[kb], o2[dt]);
            }
        __builtin_amdgcn_s_setprio(0);

        if (jt + 1 < nt) {   // write next tile into the other buffer
            *(uint4*)(&Ksh[cur ^ 1][0][sr][sp]) = kr0;
            *(uint4*)(&Ksh[cur ^ 1][1][sr][sp]) = kr1;
            *(uint4*)(&Vsh[cur ^ 1][0][sr][sp]) = vr0;
            *(uint4*)(&Vsh[cur ^ 1][1][sr][sp]) = vr1;
        }
        __syncthreads();   // ONE sync/tile: covers my reads of cur + writes of cur^1
    }

    // softmax denom: sum over g (lane bits 4,5)
    li += __shfl_xor(li, 16, 64);
    li += __shfl_xor(li, 32, 64);
    const float inv = 1.0f / li;

    const size_t orow = (size_t)(b * 2048 + q0 + wid * 16 + c);
    #pragma unroll
    for (int dt = 0; dt < 4; ++dt) {
        union { bf16_t h[4]; uint2 u; } pkk;
        #pragma unroll
        for (int r = 0; r < 4; ++r) pkk.h[r] = (bf16_t)(o2[dt][r] * inv);
        *(uint2*)(&O[orow * 1024 + h * 64 + dt * 16 + g * 4]) = pkk.u;
    }
}

// ---------------------------------------------------------------------------
extern "C" void kernel_launch(void* const* d_in, const int* in_sizes, int n_in,
                              void* d_out, int out_size, void* d_ws, size_t ws_size,
                              hipStream_t stream)
{
    const void* X  = d_in[0];
    const void* Wq = d_in[1];  const void* bq = d_in[2];
    const void* Wk = d_in[3];  const void* bk = d_in[4];
    const void* Wv = d_in[5];  const void* bv = d_in[6];
    const void* Wo = d_in[7];  const void* bo = d_in[8];

    int*    flag  = (int*)d_ws;
    float*  biasF = (float*)((char*)d_ws + 16);              // [4][1024]
    bf16_t* Xb    = (bf16_t*)((char*)d_ws + 16 + 16384);     // 4096x1024
    bf16_t* Wb    = Xb  + (size_t)4096 * 1024;               // 4x 1024x1024 (q,k,v,o)
    bf16_t* QKV   = Wb  + (size_t)4 * 1024 * 1024;           // 4096x3072 (V cols unused)
    bf16_t* Vt    = QKV + (size_t)4096 * 3072;               // 32x64x2048
    bf16_t* Ao    = Vt  + (size_t)4096 * 1024;               // 4096x1024

    const size_t MW = (size_t)1024 * 1024;

    cvt_all<<<4098, 256, 0, stream>>>(X, Wq, Wk, Wv, Wo, bq, bk, bv, bo,
                                      Xb, Wb, biasF, flag);

    gemm_qkv<<<dim3(16, 16), 512, 0, stream>>>(Xb, Wb, biasF, QKV, Vt);
    attn_kernel<<<dim3(32, 32), 256, 0, stream>>>(QKV, Vt, Ao);
    gemm_op<<<dim3(32, 8), 512, 0, stream>>>(
        Ao, Wb + 3 * MW, biasF + 3072, d_out, flag);
}

// Round 14
// 185.769 us; speedup vs baseline: 1.0720x; 1.0720x over previous
//
#include <hip/hip_runtime.h>
#include <hip/hip_bf16.h>

typedef __bf16 bf16_t;
typedef __bf16 bf16x8 __attribute__((ext_vector_type(8)));
typedef float  f32x4  __attribute__((ext_vector_type(4)));
typedef unsigned short ushort_t;

#define MFMA16(a, b, c) __builtin_amdgcn_mfma_f32_16x16x32_bf16((a), (b), (c), 0, 0, 0)
// async global->LDS, 16B/lane, dst = wave-uniform base + lane*16
#define GLDS16(g, l) __builtin_amdgcn_global_load_lds( \
    (const __attribute__((address_space(1))) unsigned int*)(g), \
    (__attribute__((address_space(3))) unsigned int*)(l), 16, 0, 0)

// s_waitcnt imm (gfx9): vmcnt[3:0] | exp[6:4] | lgkm[11:8] | vmcnt_hi[15:14]
#define WAITCNT_VM(n)  (0x0F70 | (n))   // vmcnt(n), exp/lgkm no-wait (n<16)
#define WAITCNT_LGKM0  0xC07F           // lgkmcnt(0), vm/exp no-wait

#define MEMFENCE asm volatile("" ::: "memory")

// granule swizzle for 8-elem (16B) granules within a [..][32] LDS row:
// global granule b of row r stored at position b ^ SWZ(r).
#define SWZ(r) ((((r) >> 1) ^ ((r) >> 3)) & 3)

// Problem: B=2, S=2048, D=1024, H=16, HD=64, M = B*S = 4096
// Softmax scale folded into Q at QKV epilogue: 0.125 * log2(e)
#define QSCALE 0.18033688f

// ---------------------------------------------------------------------------
// Fused conversion: local dtype-sniff per block (no extra dispatch), then
// X (2048 blocks) | weights (2048 blocks) | biases+flag (2 blocks).
// ---------------------------------------------------------------------------
__global__ __launch_bounds__(256) void cvt_all(
    const void* __restrict__ X,  const void* __restrict__ W0, const void* __restrict__ W1,
    const void* __restrict__ W2, const void* __restrict__ W3,
    const void* __restrict__ c0, const void* __restrict__ c1,
    const void* __restrict__ c2, const void* __restrict__ c3,
    bf16_t* __restrict__ Xb, bf16_t* __restrict__ Wb, float* __restrict__ biasF,
    int* __restrict__ flag)
{
    const int tid  = threadIdx.x;
    const int lane = tid & 63;
    const ushort_t u = ((const ushort_t*)X)[2 * lane];
    const int e = (u >> 7) & 0xFF;
    const int f = (__ballot(e >= 0xA0) != 0ull) ? 1 : 0;

    const int bid = blockIdx.x;
    if (bid >= 4096) {   // bias blocks
        if (bid == 4096 && tid == 0) *flag = f;
        const int idx = ((bid - 4096) * 256 + tid) * 8;   // 0..4095, chunks of 8
        const int w = idx >> 10, off = idx & 1023;
        const void* src = (w == 0) ? c0 : (w == 1) ? c1 : (w == 2) ? c2 : c3;
        #pragma unroll
        for (int r = 0; r < 8; ++r)
            biasF[idx + r] = f ? ((const float*)src)[off + r]
                               : (float)((const bf16_t*)src)[off + r];
        return;
    }

    const long long i = (long long)bid * 2048 + tid * 8;
    const void* src;
    bf16_t* dst;
    long long off;
    if (i < 4194304) { src = X; dst = Xb; off = i; }
    else {
        const int w = (int)((i - 4194304) >> 20);
        off = (i - 4194304) & 1048575;
        src = (w == 0) ? W0 : (w == 1) ? W1 : (w == 2) ? W2 : W3;
        dst = Wb + (size_t)w * 1048576;
    }
    if (f) {
        const float* s = (const float*)src + off;
        const float4 a = *(const float4*)(s);
        const float4 b = *(const float4*)(s + 4);
        bf16x8 o;
        o[0] = (bf16_t)a.x; o[1] = (bf16_t)a.y; o[2] = (bf16_t)a.z; o[3] = (bf16_t)a.w;
        o[4] = (bf16_t)b.x; o[5] = (bf16_t)b.y; o[6] = (bf16_t)b.z; o[7] = (bf16_t)b.w;
        *(bf16x8*)(dst + off) = o;
    } else {
        *(bf16x8*)(dst + off) = *(const bf16x8*)((const bf16_t*)src + off);
    }
}

// ---------------------------------------------------------------------------
// QKV GEMM (r9 structure, frozen): 256x192 tile -> grid (16,16) = 256 blocks
// = 1/CU, all CUs busy. One barrier per 32-col half; stacked Wb[3072][1024]
// and biasF[3072]; wave-dependent counted vmcnt. LDS 112KB.
// Measured: 44.3-46.2 us, MfmaUtil ~21, 0 bank conflicts. Plateau.
// ---------------------------------------------------------------------------
__global__ __launch_bounds__(512, 2) void gemm_qkv(
    const bf16_t* __restrict__ A,
    const bf16_t* __restrict__ Wst,      // stacked [3072][1024]
    const float* __restrict__ biasAll,   // stacked [3072]
    bf16_t* __restrict__ C, bf16_t* __restrict__ Vt)
{
    __shared__ bf16_t Ash[4][256 * 32];
    __shared__ bf16_t Bsh[4][192 * 32];

    const int tid  = threadIdx.x;
    const int wid  = tid >> 6;       // 0..7
    const int lane = tid & 63;
    const int g    = lane >> 4;
    const int c    = lane & 15;

    const int m0 = blockIdx.x * 256;
    const int n0 = blockIdx.y * 192;

    // staging: one GLDS call = 16 rows x 32 cols (1KB)
    const int srow = lane >> 2;                        // 0..15
    const int sblk = (lane & 3) ^ ((lane >> 3) & 3);   // pre-swizzled source blk
    const bf16_t* Ag  = A   + (size_t)(m0 + wid * 32 + srow) * 1024 + sblk * 8;
    const bf16_t* Wg0 = Wst + (size_t)(n0 + wid * 16 + srow) * 1024 + sblk * 8;
    const bf16_t* Wg1 = Wst + (size_t)(n0 + 128 + wid * 16 + srow) * 1024 + sblk * 8;

    const int waveM = (wid >> 2) * 128;   // 2 waves in M
    const int waveN = (wid & 3) * 48;     // 4 waves in N (48 cols each)
    const int fblk  = (g ^ ((c >> 1) & 3)) * 8;

    f32x4 acc[8][3] = {};

    auto stage = [&](int H) {
        const int buf = H & 3;
        GLDS16(Ag + H * 32,                      &Ash[buf][(wid * 32) * 32]);
        GLDS16(Ag + (size_t)16 * 1024 + H * 32,  &Ash[buf][(wid * 32 + 16) * 32]);
        GLDS16(Wg0 + H * 32,                     &Bsh[buf][(wid * 16) * 32]);
        if (wid < 4)
            GLDS16(Wg1 + H * 32,                 &Bsh[buf][(128 + wid * 16) * 32]);
    };

    // prologue: halves 0,1,2 in flight; retire half 0 only (2 halves stay out)
    stage(0); stage(1); stage(2);
    if (wid < 4) __builtin_amdgcn_s_waitcnt(WAITCNT_VM(8));
    else         __builtin_amdgcn_s_waitcnt(WAITCNT_VM(6));
    __builtin_amdgcn_s_barrier();
    MEMFENCE;

    #pragma unroll 4
    for (int H = 0; H < 32; ++H) {
        const int buf = H & 3;
        const bf16_t* As = Ash[buf];
        const bf16_t* Bs = Bsh[buf];

        bf16x8 bfr[3], af[8];
        #pragma unroll
        for (int j = 0; j < 3; ++j)
            bfr[j] = *(const bf16x8*)(&Bs[(waveN + j * 16 + c) * 32 + fblk]);
        #pragma unroll
        for (int i = 0; i < 8; ++i)
            af[i] = *(const bf16x8*)(&As[(waveM + i * 16 + c) * 32 + fblk]);

        if (H < 29) stage(H + 3);

        __builtin_amdgcn_s_setprio(1);
        #pragma unroll
        for (int i = 0; i < 8; ++i)
            #pragma unroll
            for (int j = 0; j < 3; ++j)
                acc[i][j] = MFMA16(af[i], bfr[j], acc[i][j]);
        __builtin_amdgcn_s_setprio(0);

        MEMFENCE;
        __builtin_amdgcn_s_waitcnt(WAITCNT_LGKM0);   // my LDS reads retired
        if (H < 29) {        // half H+1 resident (2 halves' loads may remain)
            if (wid < 4) __builtin_amdgcn_s_waitcnt(WAITCNT_VM(8));
            else         __builtin_amdgcn_s_waitcnt(WAITCNT_VM(6));
        } else if (H == 29) {
            if (wid < 4) __builtin_amdgcn_s_waitcnt(WAITCNT_VM(4));
            else         __builtin_amdgcn_s_waitcnt(WAITCNT_VM(3));
        } else if (H == 30) {
            __builtin_amdgcn_s_waitcnt(WAITCNT_VM(0));
        }
        __builtin_amdgcn_s_barrier();
        MEMFENCE;
    }

    #pragma unroll
    for (int j = 0; j < 3; ++j) {
        const int cg0 = n0 + waveN + j * 16;      // 16-aligned -> uniform branch
        const int col = cg0 + c;
        const float bv = biasAll[col];
        if (cg0 >= 2048) {
            // V^T: Vt[((b*16+h)*64 + d)*2048 + s]; 4 consecutive s per store
            const int hcol = col - 2048;
            const int h = hcol >> 6, d = hcol & 63;
            #pragma unroll
            for (int i = 0; i < 8; ++i) {
                const int row = m0 + waveM + i * 16 + g * 4;
                const int bb = row >> 11, s = row & 2047;
                bf16_t pk[4];
                #pragma unroll
                for (int r = 0; r < 4; ++r) pk[r] = (bf16_t)(acc[i][j][r] + bv);
                *(uint2*)(&Vt[(((size_t)bb * 16 + h) * 64 + d) * 2048 + s]) = *(uint2*)pk;
            }
        } else {
            const float os = (cg0 < 1024) ? QSCALE : 1.0f;   // pre-scale Q
            #pragma unroll
            for (int i = 0; i < 8; ++i) {
                const int row = m0 + waveM + i * 16 + g * 4;
                #pragma unroll
                for (int r = 0; r < 4; ++r)
                    C[(size_t)(row + r) * 3072 + col] = (bf16_t)((acc[i][j][r] + bv) * os);
            }
        }
    }
}

// ---------------------------------------------------------------------------
// Out-proj GEMM (r12, frozen): 128x128 tile, BK=64 -> 16 K-steps, grid
// (32,8) = 256 blocks = 1/CU, 3 LDS buffers (96KB), 2-deep counted prefetch.
// ---------------------------------------------------------------------------
__global__ __launch_bounds__(512, 1) void gemm_op(
    const bf16_t* __restrict__ A,
    const bf16_t* __restrict__ W,
    const float* __restrict__ bs,
    void* __restrict__ C,
    const int* __restrict__ flag)
{
    __shared__ bf16_t As[3][2][128 * 32];   // [buf][khalf][row*32]
    __shared__ bf16_t Bs[3][2][128 * 32];

    const int f32out = *flag;

    const int tid  = threadIdx.x;
    const int wid  = tid >> 6;       // 0..7
    const int lane = tid & 63;
    const int g    = lane >> 4;
    const int c    = lane & 15;

    const int m0 = blockIdx.x * 128;
    const int n0 = blockIdx.y * 128;

    // staging: one GLDS call = 16 rows x 32 cols (1KB); wave w -> rows w*16..+15
    const int srow = lane >> 2;                        // 0..15
    const int sblk = (lane & 3) ^ ((lane >> 3) & 3);   // pre-swizzled source blk
    const bf16_t* Ag = A + (size_t)(m0 + wid * 16 + srow) * 1024 + sblk * 8;
    const bf16_t* Wg = W + (size_t)(n0 + wid * 16 + srow) * 1024 + sblk * 8;

    const int waveM = (wid >> 2) * 64;    // 2 waves in M (64 rows each)
    const int waveN = (wid & 3) * 32;     // 4 waves in N (32 cols each)
    const int fblk  = (g ^ ((c >> 1) & 3)) * 8;

    f32x4 acc[4][2] = {};

    auto stage = [&](int t) {              // t = K-step (64 cols); 4 calls/wave
        const int buf = t % 3;
        const size_t k0 = (size_t)t * 64;
        GLDS16(Ag + k0,      &As[buf][0][(wid * 16) * 32]);
        GLDS16(Ag + k0 + 32, &As[buf][1][(wid * 16) * 32]);
        GLDS16(Wg + k0,      &Bs[buf][0][(wid * 16) * 32]);
        GLDS16(Wg + k0 + 32, &Bs[buf][1][(wid * 16) * 32]);
    };

    // prologue: steps 0,1 in flight; retire step 0 only (1 buffer stays out)
    stage(0); stage(1);
    __builtin_amdgcn_s_waitcnt(WAITCNT_VM(4));
    __builtin_amdgcn_s_barrier();
    MEMFENCE;

    #pragma unroll 3
    for (int s = 0; s < 16; ++s) {
        const int buf = s % 3;

        if (s < 14) stage(s + 2);

        __builtin_amdgcn_s_setprio(1);
        #pragma unroll
        for (int kh = 0; kh < 2; ++kh) {
            bf16x8 af[4], bfr[2];
            #pragma unroll
            for (int i = 0; i < 4; ++i)
                af[i] = *(const bf16x8*)(&As[buf][kh][(waveM + i * 16 + c) * 32 + fblk]);
            #pragma unroll
            for (int j = 0; j < 2; ++j)
                bfr[j] = *(const bf16x8*)(&Bs[buf][kh][(waveN + j * 16 + c) * 32 + fblk]);
            #pragma unroll
            for (int i = 0; i < 4; ++i)
                #pragma unroll
                for (int j = 0; j < 2; ++j)
                    acc[i][j] = MFMA16(af[i], bfr[j], acc[i][j]);
        }
        __builtin_amdgcn_s_setprio(0);

        MEMFENCE;
        __builtin_amdgcn_s_waitcnt(WAITCNT_LGKM0);              // my LDS reads retired
        if (s < 14)       __builtin_amdgcn_s_waitcnt(WAITCNT_VM(4));  // step s+1 resident
        else if (s == 14) __builtin_amdgcn_s_waitcnt(WAITCNT_VM(0));
        __builtin_amdgcn_s_barrier();
        MEMFENCE;
    }

    #pragma unroll
    for (int j = 0; j < 2; ++j) {
        const int col = n0 + waveN + j * 16 + c;
        const float bv = bs[col];
        #pragma unroll
        for (int i = 0; i < 4; ++i) {
            const int row = m0 + waveM + i * 16 + g * 4;
            #pragma unroll
            for (int r = 0; r < 4; ++r) {
                const float val = acc[i][j][r] + bv;
                const size_t idx = (size_t)(row + r) * 1024 + col;
                if (f32out) ((float*)C)[idx] = val;
                else        ((bf16_t*)C)[idx] = (bf16_t)val;
            }
        }
    }
}

// ---------------------------------------------------------------------------
// Causal flash attention (r11 version, reverted-to after r13 falsification):
// swapped-operand form. MFMA(kf, aq) gives lane (g,c) the P row q=c ->
// softmax lane-local; P as 4 packed uint2 into chunk-swizzled padded-72
// rows; PV swapped: o2 = MFMA(vf, pb). ~40us est.
// r13 lesson: SQ_LDS_BANK_CONFLICT here is cross-wave/block contention at
// 4-5 blocks/CU (it ROSE when the P path was deleted); r11's win over r9 was
// LDS instruction-count reduction (16 scalar writes -> 4 packed), and the
// shfl-based P redistribution put 16 cross-lane VALU ops on the critical
// path (-17us). Do not chase this counter further.
// ---------------------------------------------------------------------------
__global__ __launch_bounds__(256, 4) void attn_kernel(
    const bf16_t* __restrict__ QKV, const bf16_t* __restrict__ Vt,
    bf16_t* __restrict__ O)
{
    __shared__ bf16_t Ksh[2][64][32];
    __shared__ bf16_t Vsh[2][64][32];
    __shared__ bf16_t Psh[4][16][72];   // per wave: [q row][64 keys + 8 pad]

    const int tid  = threadIdx.x;
    const int wid  = tid >> 6;
    const int lane = tid & 63;
    const int g    = lane >> 4;
    const int c    = lane & 15;

    const int bh = blockIdx.y;
    const int b  = bh >> 4, h = bh & 15;
    const int qt = (bh < 16) ? blockIdx.x : (31 - blockIdx.x);
    const int q0 = qt * 64;
    const int nt = qt + 1;   // # of 64-key tiles

    bf16x8 aq[2];
    {
        const bf16_t* qp = QKV + (size_t)(b * 2048 + q0 + wid * 16 + c) * 3072 + h * 64;
        aq[0] = *(const bf16x8*)(qp + g * 8);
        aq[1] = *(const bf16x8*)(qp + 32 + g * 8);
    }

    float li = 0.0f;     // partial softmax denom for q = c (lane-local row)
    f32x4 o2[4] = {};    // o2[dt][r] = O[q=c][d = dt*16 + g*4 + r]

    // staging: thread -> row sr (0..63), granules j4 (plane 0) and j4+4 (plane 1)
    const int sr = tid >> 2;
    const int j4 = tid & 3;
    const bf16_t* Kg = QKV + (size_t)(b * 2048 + sr) * 3072 + 1024 + h * 64 + j4 * 8;
    const bf16_t* Vg = Vt + ((size_t)bh * 64 + sr) * 2048 + j4 * 8;

    const int sp = (j4 ^ SWZ(sr)) * 8;   // swizzled granule pos (same both planes)
    bf16_t* kd0 = &Ksh[0][sr][sp];
    bf16_t* kd1 = &Ksh[1][sr][sp];
    bf16_t* vd0 = &Vsh[0][sr][sp];
    bf16_t* vd1 = &Vsh[1][sr][sp];

    uint4 kr0 = *(const uint4*)(Kg);
    uint4 kr1 = *(const uint4*)(Kg + 32);
    uint4 vr0 = *(const uint4*)(Vg);
    uint4 vr1 = *(const uint4*)(Vg + 32);

    const int qg = q0 + wid * 16 + c;    // this lane's global q row

    for (int jt = 0; jt < nt; ++jt) {
        *(uint4*)kd0 = kr0;
        *(uint4*)kd1 = kr1;
        *(uint4*)vd0 = vr0;
        *(uint4*)vd1 = vr1;
        __syncthreads();

        if (jt + 1 < nt) {
            const size_t ko = (size_t)(jt + 1) * 64 * 3072;
            kr0 = *(const uint4*)(Kg + ko);
            kr1 = *(const uint4*)(Kg + ko + 32);
            vr0 = *(const uint4*)(Vg + (jt + 1) * 64);
            vr1 = *(const uint4*)(Vg + (jt + 1) * 64 + 32);
        }

        // QK^T swapped: s[n] = S^T fragment; lane holds S[q=c][key n*16+g*4+r]
        f32x4 s[4] = {};
        __builtin_amdgcn_s_setprio(1);
        #pragma unroll
        for (int n = 0; n < 4; ++n)
            #pragma unroll
            for (int kb = 0; kb < 2; ++kb) {
                const int row = n * 16 + c;
                const bf16x8 kf = *(const bf16x8*)(&Ksh[kb][row][(g ^ SWZ(row)) * 8]);
                s[n] = MFMA16(kf, aq[kb], s[n]);
            }
        __builtin_amdgcn_s_setprio(0);

        if (jt == nt - 1) {   // diagonal tile: mask key > q
            const int j0 = jt * 64;
            #pragma unroll
            for (int n = 0; n < 4; ++n)
                #pragma unroll
                for (int r = 0; r < 4; ++r)
                    if (j0 + n * 16 + g * 4 + r > qg) s[n][r] = -1e30f;
        }

        // softmax + packed P write (chunk swizzle + padded stride, <=2-way)
        #pragma unroll
        for (int n = 0; n < 4; ++n) {
            const float p0 = __builtin_amdgcn_exp2f(s[n][0]);
            const float p1 = __builtin_amdgcn_exp2f(s[n][1]);
            const float p2 = __builtin_amdgcn_exp2f(s[n][2]);
            const float p3 = __builtin_amdgcn_exp2f(s[n][3]);
            li += (p0 + p1) + (p2 + p3);
            union { bf16_t h[4]; uint2 u; } pk;
            pk.h[0] = (bf16_t)p0; pk.h[1] = (bf16_t)p1;
            pk.h[2] = (bf16_t)p2; pk.h[3] = (bf16_t)p3;
            const int pw = ((n ^ (c >> 2)) << 2) + (g ^ (c & 3));
            *(uint2*)(&Psh[wid][c][pw * 4]) = pk.u;
        }
        __builtin_amdgcn_wave_barrier();   // Psh wave-private; DS in-order

        // PV swapped: pb = P^T B-fragment (keys kb*32+g*8..+7 of row q=c)
        bf16x8 pb[2];
        #pragma unroll
        for (int kb = 0; kb < 2; ++kb) {
            const int n0  = 2 * kb + (g >> 1);
            const int gs  = (g & 1) * 2;
            const int base = ((n0 ^ (c >> 2)) << 2);
            const uint2 w0 = *(const uint2*)(&Psh[wid][c][(base + (gs ^ (c & 3))) * 4]);
            const uint2 w1 = *(const uint2*)(&Psh[wid][c][(base + ((gs + 1) ^ (c & 3))) * 4]);
            union { uint4 u; bf16x8 v; } cvt;
            cvt.u.x = w0.x; cvt.u.y = w0.y; cvt.u.z = w1.x; cvt.u.w = w1.y;
            pb[kb] = cvt.v;
        }

        __builtin_amdgcn_s_setprio(1);
        #pragma unroll
        for (int kb = 0; kb < 2; ++kb)
            #pragma unroll
            for (int dt = 0; dt < 4; ++dt) {
                const int row = dt * 16 + c;
                const bf16x8 vf = *(const bf16x8*)(&Vsh[kb][row][(g ^ SWZ(row)) * 8]);
                o2[dt] = MFMA16(vf, pb[kb], o2[dt]);
            }
        __builtin_amdgcn_s_setprio(0);
        __syncthreads();
    }

    // softmax denom: sum over g (lane bits 4,5)
    li += __shfl_xor(li, 16, 64);
    li += __shfl_xor(li, 32, 64);
    const float inv = 1.0f / li;

    const size_t orow = (size_t)(b * 2048 + q0 + wid * 16 + c);
    #pragma unroll
    for (int dt = 0; dt < 4; ++dt) {
        union { bf16_t h[4]; uint2 u; } pk;
        #pragma unroll
        for (int r = 0; r < 4; ++r) pk.h[r] = (bf16_t)(o2[dt][r] * inv);
        *(uint2*)(&O[orow * 1024 + h * 64 + dt * 16 + g * 4]) = pk.u;
    }
}

// ---------------------------------------------------------------------------
extern "C" void kernel_launch(void* const* d_in, const int* in_sizes, int n_in,
                              void* d_out, int out_size, void* d_ws, size_t ws_size,
                              hipStream_t stream)
{
    const void* X  = d_in[0];
    const void* Wq = d_in[1];  const void* bq = d_in[2];
    const void* Wk = d_in[3];  const void* bk = d_in[4];
    const void* Wv = d_in[5];  const void* bv = d_in[6];
    const void* Wo = d_in[7];  const void* bo = d_in[8];

    int*    flag  = (int*)d_ws;
    float*  biasF = (float*)((char*)d_ws + 16);              // [4][1024]
    bf16_t* Xb    = (bf16_t*)((char*)d_ws + 16 + 16384);     // 4096x1024
    bf16_t* Wb    = Xb  + (size_t)4096 * 1024;               // 4x 1024x1024 (q,k,v,o)
    bf16_t* QKV   = Wb  + (size_t)4 * 1024 * 1024;           // 4096x3072 (V cols unused)
    bf16_t* Vt    = QKV + (size_t)4096 * 3072;               // 32x64x2048
    bf16_t* Ao    = Vt  + (size_t)4096 * 1024;               // 4096x1024

    const size_t MW = (size_t)1024 * 1024;

    cvt_all<<<4098, 256, 0, stream>>>(X, Wq, Wk, Wv, Wo, bq, bk, bv, bo,
                                      Xb, Wb, biasF, flag);

    gemm_qkv<<<dim3(16, 16), 512, 0, stream>>>(Xb, Wb, biasF, QKV, Vt);
    attn_kernel<<<dim3(32, 32), 256, 0, stream>>>(QKV, Vt, Ao);
    gemm_op<<<dim3(32, 8), 512, 0, stream>>>(
        Ao, Wb + 3 * MW, biasF + 3072, d_out, flag);
}